// Round 1
// baseline (1223.032 us; speedup 1.0000x reference)
//
#include <hip/hip_runtime.h>
#include <hip/hip_bf16.h>

// GraphSAGE 2-layer, f32, transform-then-aggregate + CSR gather.
// N=100000 nodes, E=3.2M edges, IN=256, H=128, OUT=64.

#define AGG_BLOCK 256

// ---------------- degree histogram ----------------
__global__ __launch_bounds__(256) void k_deg(const int* __restrict__ dst, int E, int* __restrict__ cnt) {
    int e = blockIdx.x * blockDim.x + threadIdx.x;
    if (e < E) atomicAdd(&cnt[dst[e]], 1);
}

// ---------------- scan (3-kernel, chunks of 4096) ----------------
__global__ __launch_bounds__(256) void k_blocksums(const int* __restrict__ cnt, int N, int* __restrict__ bsums) {
    int b = blockIdx.x, tid = threadIdx.x;
    int base = b * 4096 + tid * 16;
    int s = 0;
    #pragma unroll
    for (int i = 0; i < 16; ++i) { int idx = base + i; if (idx < N) s += cnt[idx]; }
    __shared__ int sd[256];
    sd[tid] = s; __syncthreads();
    for (int off = 128; off > 0; off >>= 1) { if (tid < off) sd[tid] += sd[tid + off]; __syncthreads(); }
    if (tid == 0) bsums[b] = sd[0];
}

__global__ void k_scantop(const int* __restrict__ bsums, int nb, int* __restrict__ boffs,
                          int* __restrict__ row_start, int N, int E) {
    if (threadIdx.x == 0 && blockIdx.x == 0) {
        int run = 0;
        for (int i = 0; i < nb; ++i) { boffs[i] = run; run += bsums[i]; }
        row_start[N] = E;
    }
}

__global__ __launch_bounds__(256) void k_scanwrite(const int* __restrict__ cnt, int N,
                                                   const int* __restrict__ boffs,
                                                   int* __restrict__ row_start, int* __restrict__ row_fill,
                                                   float* __restrict__ deg_inv) {
    int b = blockIdx.x, tid = threadIdx.x;
    int base = b * 4096 + tid * 16;
    int local[16];
    int s = 0;
    #pragma unroll
    for (int i = 0; i < 16; ++i) {
        int idx = base + i;
        int c = (idx < N) ? cnt[idx] : 0;
        local[i] = c; s += c;
    }
    __shared__ int sd[256];
    sd[tid] = s; __syncthreads();
    // Hillis-Steele inclusive scan over 256 thread sums
    for (int off = 1; off < 256; off <<= 1) {
        int v = (tid >= off) ? sd[tid - off] : 0;
        __syncthreads();
        sd[tid] += v;
        __syncthreads();
    }
    int run = boffs[b] + sd[tid] - s;   // exclusive prefix for this thread
    #pragma unroll
    for (int i = 0; i < 16; ++i) {
        int idx = base + i;
        if (idx < N) {
            row_start[idx] = run;
            row_fill[idx]  = run;
            int d = local[i] > 1 ? local[i] : 1;
            deg_inv[idx] = 1.0f / (float)d;
            run += local[i];
        }
    }
}

// ---------------- counting-sort scatter of edges ----------------
__global__ __launch_bounds__(256) void k_scatter(const int* __restrict__ src, const int* __restrict__ dst,
                                                 int E, int* __restrict__ row_fill, int* __restrict__ src_sorted) {
    int e = blockIdx.x * blockDim.x + threadIdx.x;
    if (e < E) {
        int pos = atomicAdd(&row_fill[dst[e]], 1);
        src_sorted[pos] = src[e];
    }
}

// ---------------- tiled f32 GEMM:  C[N x 2*halfC] = A[N x K] @ [W0 | W1] ----------------
// BM=64, BN=64, BK=16, 256 threads, 4x4 micro-tile per thread.
#define BM 64
#define BN 64
#define BK 16

__global__ __launch_bounds__(256) void gemm_cat(const float* __restrict__ A, int N, int K,
                                                const float* __restrict__ W0, const float* __restrict__ W1,
                                                int halfC, float* __restrict__ C) {
    const int Ccols = 2 * halfC;
    const int m0 = blockIdx.x * BM;
    const int n0 = blockIdx.y * BN;
    const float* __restrict__ Wsrc = (n0 < halfC) ? W0 : W1;
    const int nb = (n0 < halfC) ? n0 : (n0 - halfC);

    __shared__ float As[BK][BM + 4];   // transposed A tile; +4 pad keeps 16B align, kills bank conflicts
    __shared__ float Bs[BK][BN];

    const int tid = threadIdx.x;
    const int tx = tid & 15, ty = tid >> 4;

    // A-load mapping: thread -> (row, k-quad)
    const int ar  = tid >> 2;          // 0..63
    const int akq = (tid & 3) * 4;     // 0,4,8,12
    // B-load mapping: thread -> (k, col-quad)
    const int bk = tid >> 4;           // 0..15
    const int bc = (tid & 15) * 4;     // 0..60

    float acc[4][4] = {};

    for (int k0 = 0; k0 < K; k0 += BK) {
        float4 av = make_float4(0.f, 0.f, 0.f, 0.f);
        int grow = m0 + ar;
        if (grow < N) av = *reinterpret_cast<const float4*>(&A[(size_t)grow * K + k0 + akq]);
        As[akq + 0][ar] = av.x;
        As[akq + 1][ar] = av.y;
        As[akq + 2][ar] = av.z;
        As[akq + 3][ar] = av.w;

        float4 bv = *reinterpret_cast<const float4*>(&Wsrc[(size_t)(k0 + bk) * halfC + nb + bc]);
        *reinterpret_cast<float4*>(&Bs[bk][bc]) = bv;

        __syncthreads();
        #pragma unroll
        for (int kk = 0; kk < BK; ++kk) {
            float4 a4 = *reinterpret_cast<const float4*>(&As[kk][ty * 4]);
            float4 b4 = *reinterpret_cast<const float4*>(&Bs[kk][tx * 4]);
            float aa[4] = {a4.x, a4.y, a4.z, a4.w};
            float bb[4] = {b4.x, b4.y, b4.z, b4.w};
            #pragma unroll
            for (int i = 0; i < 4; ++i)
                #pragma unroll
                for (int j = 0; j < 4; ++j)
                    acc[i][j] = fmaf(aa[i], bb[j], acc[i][j]);
        }
        __syncthreads();
    }

    #pragma unroll
    for (int i = 0; i < 4; ++i) {
        int grow = m0 + ty * 4 + i;
        if (grow < N) {
            float4 v = make_float4(acc[i][0], acc[i][1], acc[i][2], acc[i][3]);
            *reinterpret_cast<float4*>(&C[(size_t)grow * Ccols + n0 + tx * 4]) = v;
        }
    }
}

// ---------------- layer-1 aggregation + combine + relu ----------------
// t1 layout: [N][256], cols 0..127 = x@W1_self, cols 128..255 = x@W1_neigh
// one wave per node; lane holds 2 features (float2)
__global__ __launch_bounds__(AGG_BLOCK) void k_agg1(const float* __restrict__ t1,
                                                    const int* __restrict__ row_start,
                                                    const int* __restrict__ src_sorted,
                                                    const float* __restrict__ deg_inv,
                                                    const float* __restrict__ b1,
                                                    float* __restrict__ h, int N) {
    int wid  = (blockIdx.x * blockDim.x + threadIdx.x) >> 6;
    int lane = threadIdx.x & 63;
    if (wid >= N) return;
    int e0 = row_start[wid], e1 = row_start[wid + 1];
    float2 acc = make_float2(0.f, 0.f);
    for (int e = e0; e < e1; ++e) {
        int s = src_sorted[e];
        float2 v = *reinterpret_cast<const float2*>(&t1[(size_t)s * 256 + 128 + lane * 2]);
        acc.x += v.x; acc.y += v.y;
    }
    float dinv = deg_inv[wid];
    float2 self = *reinterpret_cast<const float2*>(&t1[(size_t)wid * 256 + lane * 2]);
    float2 bb   = *reinterpret_cast<const float2*>(&b1[lane * 2]);
    float hx = fmaf(acc.x, dinv, self.x) + bb.x;
    float hy = fmaf(acc.y, dinv, self.y) + bb.y;
    hx = fmaxf(hx, 0.f); hy = fmaxf(hy, 0.f);
    *reinterpret_cast<float2*>(&h[(size_t)wid * 128 + lane * 2]) = make_float2(hx, hy);
}

// ---------------- layer-2 aggregation + combine (no relu) ----------------
// t2 layout: [N][128], cols 0..63 = h@W2_self, cols 64..127 = h@W2_neigh
__global__ __launch_bounds__(AGG_BLOCK) void k_agg2(const float* __restrict__ t2,
                                                    const int* __restrict__ row_start,
                                                    const int* __restrict__ src_sorted,
                                                    const float* __restrict__ deg_inv,
                                                    const float* __restrict__ b2,
                                                    float* __restrict__ out, int N) {
    int wid  = (blockIdx.x * blockDim.x + threadIdx.x) >> 6;
    int lane = threadIdx.x & 63;
    if (wid >= N) return;
    int e0 = row_start[wid], e1 = row_start[wid + 1];
    float acc = 0.f;
    for (int e = e0; e < e1; ++e) {
        int s = src_sorted[e];
        acc += t2[(size_t)s * 128 + 64 + lane];
    }
    out[(size_t)wid * 64 + lane] = fmaf(acc, deg_inv[wid], t2[(size_t)wid * 128 + lane]) + b2[lane];
}

extern "C" void kernel_launch(void* const* d_in, const int* in_sizes, int n_in,
                              void* d_out, int out_size, void* d_ws, size_t ws_size,
                              hipStream_t stream) {
    const float* x   = (const float*)d_in[0];
    const int*   src = (const int*)d_in[1];
    const int*   dst = (const int*)d_in[2];
    const float* W1s = (const float*)d_in[3];
    const float* W1n = (const float*)d_in[4];
    const float* b1  = (const float*)d_in[5];
    const float* W2s = (const float*)d_in[6];
    const float* W2n = (const float*)d_in[7];
    const float* b2  = (const float*)d_in[8];
    float* out = (float*)d_out;

    const int IN = 256;
    const int N  = in_sizes[0] / IN;
    const int E  = in_sizes[1];

    char* ws = (char*)d_ws;
    size_t off = 0;
    auto alloc = [&](size_t bytes) -> char* {
        char* p = ws + off;
        off = (off + bytes + 255) & ~(size_t)255;
        return p;
    };
    int*   cnt        = (int*)  alloc((size_t)N * 4);
    int*   row_start  = (int*)  alloc((size_t)(N + 1) * 4);
    int*   row_fill   = (int*)  alloc((size_t)N * 4);
    float* deg_inv    = (float*)alloc((size_t)N * 4);
    int*   bsums      = (int*)  alloc(64 * 4);
    int*   boffs      = (int*)  alloc(64 * 4);
    int*   src_sorted = (int*)  alloc((size_t)E * 4);
    float* t1         = (float*)alloc((size_t)N * 256 * 4);  // also reused as t2 [N x 128]
    float* h          = (float*)alloc((size_t)N * 128 * 4);

    // 1. CSR build
    hipMemsetAsync(cnt, 0, (size_t)N * 4, stream);
    k_deg<<<(E + 255) / 256, 256, 0, stream>>>(dst, E, cnt);
    int nb = (N + 4095) / 4096;
    k_blocksums<<<nb, 256, 0, stream>>>(cnt, N, bsums);
    k_scantop<<<1, 64, 0, stream>>>(bsums, nb, boffs, row_start, N, E);
    k_scanwrite<<<nb, 256, 0, stream>>>(cnt, N, boffs, row_start, row_fill, deg_inv);
    k_scatter<<<(E + 255) / 256, 256, 0, stream>>>(src, dst, E, row_fill, src_sorted);

    // 2. layer 1: t1 = x @ [W1_self | W1_neigh]   (N x 256)
    gemm_cat<<<dim3((N + BM - 1) / BM, 4), 256, 0, stream>>>(x, N, 256, W1s, W1n, 128, t1);
    // 3. aggregate + combine + relu -> h (N x 128)
    k_agg1<<<(N + 3) / 4, AGG_BLOCK, 0, stream>>>(t1, row_start, src_sorted, deg_inv, b1, h, N);
    // 4. layer 2: t2 = h @ [W2_self | W2_neigh]   (N x 128), reuse t1 buffer
    gemm_cat<<<dim3((N + BM - 1) / BM, 2), 256, 0, stream>>>(h, N, 128, W2s, W2n, 64, t1);
    // 5. aggregate + combine -> out (N x 64)
    k_agg2<<<(N + 3) / 4, AGG_BLOCK, 0, stream>>>(t1, row_start, src_sorted, deg_inv, b2, out, N);
}

// Round 2
// 700.262 us; speedup vs baseline: 1.7465x; 1.7465x over previous
//
#include <hip/hip_runtime.h>
#include <hip/hip_bf16.h>

// GraphSAGE 2-layer: CSR build + bf16 MFMA transform-then-aggregate.
// N=100000, E=3.2M, IN=256, H=128, OUT=64.  Mpad=100096 (pad rows = garbage, never read).

typedef unsigned int  uint32;
typedef unsigned short ushort16;
typedef __attribute__((ext_vector_type(8))) short short8;
typedef __attribute__((ext_vector_type(4))) float f32x4;

__device__ __forceinline__ unsigned short f2bf(float f) {
    unsigned u = __float_as_uint(f);
    u += 0x7fffu + ((u >> 16) & 1u);      // RNE
    return (unsigned short)(u >> 16);
}
__device__ __forceinline__ uint32 pack2bf(float lo, float hi) {
    return (uint32)f2bf(lo) | ((uint32)f2bf(hi) << 16);
}
__device__ __forceinline__ float bf_lo(uint32 v) { return __uint_as_float(v << 16); }
__device__ __forceinline__ float bf_hi(uint32 v) { return __uint_as_float(v & 0xFFFF0000u); }

// ---------------- CSR build ----------------
__global__ __launch_bounds__(256) void k_deg(const int* __restrict__ dst, int E, int* __restrict__ cnt) {
    int e = blockIdx.x * blockDim.x + threadIdx.x;
    if (e < E) atomicAdd(&cnt[dst[e]], 1);
}

__global__ __launch_bounds__(256) void k_blocksums(const int* __restrict__ cnt, int N, int* __restrict__ bsums) {
    int b = blockIdx.x, tid = threadIdx.x;
    int base = b * 4096 + tid * 16;
    int s = 0;
    #pragma unroll
    for (int i = 0; i < 16; ++i) { int idx = base + i; if (idx < N) s += cnt[idx]; }
    __shared__ int sd[256];
    sd[tid] = s; __syncthreads();
    for (int off = 128; off > 0; off >>= 1) { if (tid < off) sd[tid] += sd[tid + off]; __syncthreads(); }
    if (tid == 0) bsums[b] = sd[0];
}

__global__ void k_scantop(const int* __restrict__ bsums, int nb, int* __restrict__ boffs,
                          int* __restrict__ row_start, int N, int E) {
    if (threadIdx.x == 0 && blockIdx.x == 0) {
        int run = 0;
        for (int i = 0; i < nb; ++i) { boffs[i] = run; run += bsums[i]; }
        row_start[N] = E;
    }
}

__global__ __launch_bounds__(256) void k_scanwrite(const int* __restrict__ cnt, int N,
                                                   const int* __restrict__ boffs,
                                                   int* __restrict__ row_start, int* __restrict__ row_fill,
                                                   float* __restrict__ deg_inv) {
    int b = blockIdx.x, tid = threadIdx.x;
    int base = b * 4096 + tid * 16;
    int local[16];
    int s = 0;
    #pragma unroll
    for (int i = 0; i < 16; ++i) {
        int idx = base + i;
        int c = (idx < N) ? cnt[idx] : 0;
        local[i] = c; s += c;
    }
    __shared__ int sd[256];
    sd[tid] = s; __syncthreads();
    for (int off = 1; off < 256; off <<= 1) {
        int v = (tid >= off) ? sd[tid - off] : 0;
        __syncthreads();
        sd[tid] += v;
        __syncthreads();
    }
    int run = boffs[b] + sd[tid] - s;
    #pragma unroll
    for (int i = 0; i < 16; ++i) {
        int idx = base + i;
        if (idx < N) {
            row_start[idx] = run;
            row_fill[idx]  = run;
            int d = local[i] > 1 ? local[i] : 1;
            deg_inv[idx] = 1.0f / (float)d;
            run += local[i];
        }
    }
}

__global__ __launch_bounds__(256) void k_scatter(const int* __restrict__ src, const int* __restrict__ dst,
                                                 int E, int* __restrict__ row_fill, int* __restrict__ src_sorted) {
    int e = blockIdx.x * blockDim.x + threadIdx.x;
    if (e < E) {
        int pos = atomicAdd(&row_fill[dst[e]], 1);
        src_sorted[pos] = src[e];
    }
}

// ---------------- casts ----------------
// x f32 -> bf16, 8 elems/thread
__global__ __launch_bounds__(256) void k_cast_x(const float* __restrict__ x, uint32* __restrict__ xb, long total8) {
    long t = (long)blockIdx.x * blockDim.x + threadIdx.x;
    if (t >= total8) return;
    const float4* p = reinterpret_cast<const float4*>(x) + t * 2;
    float4 a = p[0], b = p[1];
    uint4 o;
    o.x = pack2bf(a.x, a.y); o.y = pack2bf(a.z, a.w);
    o.z = pack2bf(b.x, b.y); o.w = pack2bf(b.z, b.w);
    reinterpret_cast<uint4*>(xb)[t] = o;
}

// transpose+cast weights: Wt[c][k] = (c<halfC ? Ws[k][c] : Wn[k][c-halfC]), row-major [2*halfC][K]
__global__ __launch_bounds__(256) void k_wt(const float* __restrict__ Ws, const float* __restrict__ Wn,
                                            int K, int logK, int halfC, unsigned short* __restrict__ Wt) {
    int t = blockIdx.x * blockDim.x + threadIdx.x;
    int total = 2 * halfC * K;
    if (t >= total) return;
    int c = t >> logK, k = t & (K - 1);
    float v = (c < halfC) ? Ws[(size_t)k * halfC + c] : Wn[(size_t)k * halfC + (c - halfC)];
    Wt[t] = f2bf(v);
}

// ---------------- bf16 MFMA GEMM ----------------
// C[Mpad x 2*halfC] = A[Mpad x K](bf16) @ Wt^T.  Wt is [2*halfC][K] row-major (already transposed).
// Output split: cols < halfC -> Cself (f32), cols >= halfC -> Cneigh (bf16).
// BM=128, BN=128, BK=32, 256 threads (4 waves, 2x2), wave tile 64x64 = 4x4 x (16x16).
#define LDSK 40   // padded K-stride in shorts (80B: conflict-free, 16B-aligned)

__global__ __launch_bounds__(256) void gemm_mfma(const unsigned short* __restrict__ A, int K,
                                                 const unsigned short* __restrict__ Wt, int halfC,
                                                 float* __restrict__ Cself, unsigned short* __restrict__ Cneigh) {
    __shared__ unsigned short As[128 * LDSK];
    __shared__ unsigned short Bs[128 * LDSK];
    const int m0 = blockIdx.x * 128;
    const int n0 = blockIdx.y * 128;
    const int tid = threadIdx.x;
    const int wave = tid >> 6, lane = tid & 63;
    const int wm = wave >> 1, wn = wave & 1;
    const int l15 = lane & 15, l4 = lane >> 4;

    f32x4 acc[4][4] = {};

    for (int k0 = 0; k0 < K; k0 += 32) {
        #pragma unroll
        for (int t = 0; t < 2; ++t) {
            int task = tid + t * 256;
            int row = task >> 2, chunk = task & 3;
            const uint4 av = *reinterpret_cast<const uint4*>(&A[(size_t)(m0 + row) * K + k0 + chunk * 8]);
            *reinterpret_cast<uint4*>(&As[row * LDSK + chunk * 8]) = av;
            const uint4 bv = *reinterpret_cast<const uint4*>(&Wt[(size_t)(n0 + row) * K + k0 + chunk * 8]);
            *reinterpret_cast<uint4*>(&Bs[row * LDSK + chunk * 8]) = bv;
        }
        __syncthreads();
        short8 af[4], bfr[4];
        #pragma unroll
        for (int m = 0; m < 4; ++m)
            af[m] = *reinterpret_cast<const short8*>(&As[(wm * 64 + m * 16 + l15) * LDSK + l4 * 8]);
        #pragma unroll
        for (int n = 0; n < 4; ++n)
            bfr[n] = *reinterpret_cast<const short8*>(&Bs[(wn * 64 + n * 16 + l15) * LDSK + l4 * 8]);
        #pragma unroll
        for (int m = 0; m < 4; ++m)
            #pragma unroll
            for (int n = 0; n < 4; ++n)
                acc[m][n] = __builtin_amdgcn_mfma_f32_16x16x32_bf16(af[m], bfr[n], acc[m][n], 0, 0, 0);
        __syncthreads();
    }

    #pragma unroll
    for (int m = 0; m < 4; ++m) {
        #pragma unroll
        for (int n = 0; n < 4; ++n) {
            int cg = n0 + wn * 64 + n * 16 + l15;
            bool is_self = cg < halfC;
            #pragma unroll
            for (int r = 0; r < 4; ++r) {
                int rg = m0 + wm * 64 + m * 16 + l4 * 4 + r;
                float v = acc[m][n][r];
                if (is_self) Cself[(size_t)rg * halfC + cg] = v;
                else         Cneigh[(size_t)rg * halfC + (cg - halfC)] = f2bf(v);
            }
        }
    }
}

// ---------------- layer-1 aggregate + combine + relu -> h (bf16) ----------------
// one wave per node; lane holds 2 cols (uint32 = 2 bf16). unroll-4 gather.
__global__ __launch_bounds__(256) void k_agg1(const uint32* __restrict__ t1n, const float* __restrict__ t1s,
                                              const int* __restrict__ rs, const int* __restrict__ ss,
                                              const float* __restrict__ dinv, const float* __restrict__ b1,
                                              uint32* __restrict__ h, int N) {
    int wid  = (blockIdx.x * blockDim.x + threadIdx.x) >> 6;
    int lane = threadIdx.x & 63;
    if (wid >= N) return;
    int e0 = rs[wid], e1 = rs[wid + 1];
    float ax = 0.f, ay = 0.f, bx = 0.f, by = 0.f;
    int e = e0;
    for (; e + 4 <= e1; e += 4) {
        int s0 = ss[e], s1 = ss[e + 1], s2 = ss[e + 2], s3 = ss[e + 3];
        uint32 v0 = t1n[(size_t)s0 * 64 + lane];
        uint32 v1 = t1n[(size_t)s1 * 64 + lane];
        uint32 v2 = t1n[(size_t)s2 * 64 + lane];
        uint32 v3 = t1n[(size_t)s3 * 64 + lane];
        ax += bf_lo(v0); ay += bf_hi(v0);
        bx += bf_lo(v1); by += bf_hi(v1);
        ax += bf_lo(v2); ay += bf_hi(v2);
        bx += bf_lo(v3); by += bf_hi(v3);
    }
    for (; e < e1; ++e) {
        uint32 v = t1n[(size_t)ss[e] * 64 + lane];
        ax += bf_lo(v); ay += bf_hi(v);
    }
    ax += bx; ay += by;
    float di = dinv[wid];
    float2 self = *reinterpret_cast<const float2*>(&t1s[(size_t)wid * 128 + lane * 2]);
    float2 bb   = *reinterpret_cast<const float2*>(&b1[lane * 2]);
    float hx = fmaxf(fmaf(ax, di, self.x) + bb.x, 0.f);
    float hy = fmaxf(fmaf(ay, di, self.y) + bb.y, 0.f);
    h[(size_t)wid * 64 + lane] = pack2bf(hx, hy);
}

// ---------------- layer-2 aggregate + combine -> out (f32) ----------------
// half-wave (32 lanes) per node; lane holds 2 cols. unroll-4 gather.
__global__ __launch_bounds__(256) void k_agg2(const uint32* __restrict__ t2n, const float* __restrict__ t2s,
                                              const int* __restrict__ rs, const int* __restrict__ ss,
                                              const float* __restrict__ dinv, const float* __restrict__ b2,
                                              float* __restrict__ out, int N) {
    int node = (blockIdx.x * blockDim.x + threadIdx.x) >> 5;
    int lane = threadIdx.x & 31;
    if (node >= N) return;
    int e0 = rs[node], e1 = rs[node + 1];
    float ax = 0.f, ay = 0.f, bx = 0.f, by = 0.f;
    int e = e0;
    for (; e + 4 <= e1; e += 4) {
        int s0 = ss[e], s1 = ss[e + 1], s2 = ss[e + 2], s3 = ss[e + 3];
        uint32 v0 = t2n[(size_t)s0 * 32 + lane];
        uint32 v1 = t2n[(size_t)s1 * 32 + lane];
        uint32 v2 = t2n[(size_t)s2 * 32 + lane];
        uint32 v3 = t2n[(size_t)s3 * 32 + lane];
        ax += bf_lo(v0); ay += bf_hi(v0);
        bx += bf_lo(v1); by += bf_hi(v1);
        ax += bf_lo(v2); ay += bf_hi(v2);
        bx += bf_lo(v3); by += bf_hi(v3);
    }
    for (; e < e1; ++e) {
        uint32 v = t2n[(size_t)ss[e] * 32 + lane];
        ax += bf_lo(v); ay += bf_hi(v);
    }
    ax += bx; ay += by;
    float di = dinv[node];
    float2 self = *reinterpret_cast<const float2*>(&t2s[(size_t)node * 64 + lane * 2]);
    float2 bb   = *reinterpret_cast<const float2*>(&b2[lane * 2]);
    float2 o;
    o.x = fmaf(ax, di, self.x) + bb.x;
    o.y = fmaf(ay, di, self.y) + bb.y;
    *reinterpret_cast<float2*>(&out[(size_t)node * 64 + lane * 2]) = o;
}

extern "C" void kernel_launch(void* const* d_in, const int* in_sizes, int n_in,
                              void* d_out, int out_size, void* d_ws, size_t ws_size,
                              hipStream_t stream) {
    const float* x   = (const float*)d_in[0];
    const int*   src = (const int*)d_in[1];
    const int*   dst = (const int*)d_in[2];
    const float* W1s = (const float*)d_in[3];
    const float* W1n = (const float*)d_in[4];
    const float* b1  = (const float*)d_in[5];
    const float* W2s = (const float*)d_in[6];
    const float* W2n = (const float*)d_in[7];
    const float* b2  = (const float*)d_in[8];
    float* out = (float*)d_out;

    const int IN = 256, H = 128, OUT = 64;
    const int N  = in_sizes[0] / IN;
    const int E  = in_sizes[1];
    const int Mpad = (N + 127) & ~127;

    char* ws = (char*)d_ws;
    size_t off = 0;
    auto alloc = [&](size_t bytes) -> char* {
        char* p = ws + off;
        off = (off + bytes + 255) & ~(size_t)255;
        return p;
    };
    int*   cnt        = (int*)  alloc((size_t)N * 4);
    int*   row_start  = (int*)  alloc((size_t)(N + 1) * 4);
    int*   row_fill   = (int*)  alloc((size_t)N * 4);
    float* deg_inv    = (float*)alloc((size_t)N * 4);
    int*   bsums      = (int*)  alloc(64 * 4);
    int*   boffs      = (int*)  alloc(64 * 4);
    int*   src_sorted = (int*)  alloc((size_t)E * 4);
    unsigned short* xb  = (unsigned short*)alloc((size_t)Mpad * IN * 2);     // bf16 x
    unsigned short* Wt1 = (unsigned short*)alloc((size_t)(2 * H) * IN * 2);  // [256][256]
    unsigned short* Wt2 = (unsigned short*)alloc((size_t)(2 * OUT) * H * 2); // [128][128]
    float*          t1s = (float*)         alloc((size_t)Mpad * H * 4);      // reused as t2s [Mpad][64]
    unsigned short* t1n = (unsigned short*)alloc((size_t)Mpad * H * 2);      // reused as t2n [Mpad][64]
    unsigned short* hbf = (unsigned short*)alloc((size_t)Mpad * H * 2);      // layer-1 output, bf16

    // 1. CSR build
    hipMemsetAsync(cnt, 0, (size_t)N * 4, stream);
    k_deg<<<(E + 255) / 256, 256, 0, stream>>>(dst, E, cnt);
    int nb = (N + 4095) / 4096;
    k_blocksums<<<nb, 256, 0, stream>>>(cnt, N, bsums);
    k_scantop<<<1, 64, 0, stream>>>(bsums, nb, boffs, row_start, N, E);
    k_scanwrite<<<nb, 256, 0, stream>>>(cnt, N, boffs, row_start, row_fill, deg_inv);
    k_scatter<<<(E + 255) / 256, 256, 0, stream>>>(src, dst, E, row_fill, src_sorted);

    // 2. casts
    long total8 = (long)N * IN / 8;
    k_cast_x<<<(int)((total8 + 255) / 256), 256, 0, stream>>>(x, (uint32*)xb, total8);
    k_wt<<<(2 * H * IN + 255) / 256, 256, 0, stream>>>(W1s, W1n, IN, 8, H, Wt1);
    k_wt<<<(2 * OUT * H + 255) / 256, 256, 0, stream>>>(W2s, W2n, H, 7, OUT, Wt2);

    // 3. layer 1 GEMM: [Mpad x 256] -> self f32 [Mpad x 128] + neigh bf16 [Mpad x 128]
    gemm_mfma<<<dim3(Mpad / 128, 2), 256, 0, stream>>>(xb, IN, Wt1, H, t1s, t1n);
    // 4. aggregate + relu -> h bf16
    k_agg1<<<(N + 3) / 4, 256, 0, stream>>>((const uint32*)t1n, t1s, row_start, src_sorted, deg_inv, b1,
                                            (uint32*)hbf, N);
    // 5. layer 2 GEMM: [Mpad x 128] -> self f32 [Mpad x 64] + neigh bf16 [Mpad x 64] (reuse t1s/t1n)
    gemm_mfma<<<dim3(Mpad / 128, 1), 256, 0, stream>>>(hbf, H, Wt2, OUT, t1s, t1n);
    // 6. aggregate -> out f32
    k_agg2<<<(N + 7) / 8, 256, 0, stream>>>((const uint32*)t1n, t1s, row_start, src_sorted, deg_inv, b2,
                                            out, N);
}

// Round 3
// 424.827 us; speedup vs baseline: 2.8789x; 1.6483x over previous
//
#include <hip/hip_runtime.h>
#include <hip/hip_bf16.h>

// GraphSAGE 2-layer: bucket-sort CSR build + bf16 MFMA transform-then-aggregate.
// N=100000, E=3.2M, IN=256, H=128, OUT=64.

typedef unsigned int uint32;
typedef __attribute__((ext_vector_type(8))) short short8;
typedef __attribute__((ext_vector_type(4))) float f32x4;

#define NBMAX 1024     // max buckets (supports N <= 131072 at 128 nodes/bucket)
#define EPB   16384    // edges per block in bucket count/scatter (64/thread)

__device__ __forceinline__ unsigned short f2bf(float f) {
    unsigned u = __float_as_uint(f);
    u += 0x7fffu + ((u >> 16) & 1u);      // RNE
    return (unsigned short)(u >> 16);
}
__device__ __forceinline__ uint32 pack2bf(float lo, float hi) {
    return (uint32)f2bf(lo) | ((uint32)f2bf(hi) << 16);
}
__device__ __forceinline__ float bf_lo(uint32 v) { return __uint_as_float(v << 16); }
__device__ __forceinline__ float bf_hi(uint32 v) { return __uint_as_float(v & 0xFFFF0000u); }

// ---------------- bucket-sort CSR build ----------------
// bucket b = dst >> 7 (128 nodes per bucket)

__global__ __launch_bounds__(256) void k_bucket_count(const int* __restrict__ dst, int E,
                                                      int* __restrict__ bcnt) {
    __shared__ int hist[NBMAX];
    for (int i = threadIdx.x; i < NBMAX; i += 256) hist[i] = 0;
    __syncthreads();
    int base = blockIdx.x * EPB;
    #pragma unroll 4
    for (int i = 0; i < 64; ++i) {
        int e = base + i * 256 + threadIdx.x;
        if (e < E) atomicAdd(&hist[dst[e] >> 7], 1);
    }
    __syncthreads();
    for (int i = threadIdx.x; i < NBMAX; i += 256) {
        int h = hist[i];
        if (h) atomicAdd(&bcnt[i], h);
    }
}

__global__ __launch_bounds__(1024) void k_bucket_scan(const int* __restrict__ bcnt, int NB,
                                                      int* __restrict__ boffs, int* __restrict__ gfill,
                                                      int E) {
    __shared__ int sd[1024];
    int tid = threadIdx.x;
    int v = (tid < NB) ? bcnt[tid] : 0;
    sd[tid] = v;
    __syncthreads();
    for (int off = 1; off < 1024; off <<= 1) {
        int t = (tid >= off) ? sd[tid - off] : 0;
        __syncthreads();
        sd[tid] += t;
        __syncthreads();
    }
    int excl = sd[tid] - v;
    if (tid < NB) { boffs[tid] = excl; gfill[tid] = excl; }
    if (tid == 0) boffs[NB] = E;
}

__global__ __launch_bounds__(256) void k_bucket_scatter(const int* __restrict__ src,
                                                        const int* __restrict__ dst, int E,
                                                        int* __restrict__ gfill,
                                                        uint32* __restrict__ pairs) {
    __shared__ int hist[NBMAX];
    __shared__ int basea[NBMAX];
    for (int i = threadIdx.x; i < NBMAX; i += 256) hist[i] = 0;
    __syncthreads();
    int base = blockIdx.x * EPB;
    #pragma unroll 4
    for (int i = 0; i < 64; ++i) {
        int e = base + i * 256 + threadIdx.x;
        if (e < E) atomicAdd(&hist[dst[e] >> 7], 1);
    }
    __syncthreads();
    for (int i = threadIdx.x; i < NBMAX; i += 256) {
        int h = hist[i];
        basea[i] = h ? atomicAdd(&gfill[i], h) : 0;
        hist[i] = 0;   // reuse as per-bucket fill
    }
    __syncthreads();
    #pragma unroll 4
    for (int i = 0; i < 64; ++i) {
        int e = base + i * 256 + threadIdx.x;
        if (e < E) {
            int d = dst[e];
            int b = d >> 7;
            int pos = basea[b] + atomicAdd(&hist[b], 1);
            pairs[pos] = ((uint32)src[e] << 7) | (uint32)(d & 127);
        }
    }
}

// one block per bucket: per-node histogram + scan -> row_start/deg_inv, then local scatter
__global__ __launch_bounds__(256) void k_bucket_sort(const uint32* __restrict__ pairs,
                                                     const int* __restrict__ boffs,
                                                     int N, int E,
                                                     int* __restrict__ row_start,
                                                     float* __restrict__ deg_inv,
                                                     int* __restrict__ src_sorted) {
    __shared__ int cnt[128];
    __shared__ int sc[128];
    __shared__ int fill[128];
    int b = blockIdx.x, tid = threadIdx.x;
    int s0 = boffs[b], s1 = boffs[b + 1];
    if (tid < 128) cnt[tid] = 0;
    __syncthreads();
    for (int e = s0 + tid; e < s1; e += 256)
        atomicAdd(&cnt[pairs[e] & 127], 1);
    __syncthreads();
    if (tid < 128) sc[tid] = cnt[tid];
    __syncthreads();
    for (int off = 1; off < 128; off <<= 1) {
        int v = 0;
        if (tid < 128 && tid >= off) v = sc[tid - off];
        __syncthreads();
        if (tid < 128) sc[tid] += v;
        __syncthreads();
    }
    if (tid < 128) {
        int excl = sc[tid] - cnt[tid];
        int node = b * 128 + tid;
        if (node < N) {
            row_start[node] = s0 + excl;
            int d = cnt[tid];
            deg_inv[node] = 1.0f / (float)(d > 1 ? d : 1);
        }
        fill[tid] = s0 + excl;
    }
    if (b == 0 && tid == 0) row_start[N] = E;
    __syncthreads();
    for (int e = s0 + tid; e < s1; e += 256) {
        uint32 p = pairs[e];
        int pos = atomicAdd(&fill[p & 127], 1);
        src_sorted[pos] = (int)(p >> 7);
    }
}

// ---------------- casts ----------------
__global__ __launch_bounds__(256) void k_cast_x(const float* __restrict__ x, uint32* __restrict__ xb, long total8) {
    long t = (long)blockIdx.x * blockDim.x + threadIdx.x;
    if (t >= total8) return;
    const float4* p = reinterpret_cast<const float4*>(x) + t * 2;
    float4 a = p[0], b = p[1];
    uint4 o;
    o.x = pack2bf(a.x, a.y); o.y = pack2bf(a.z, a.w);
    o.z = pack2bf(b.x, b.y); o.w = pack2bf(b.z, b.w);
    reinterpret_cast<uint4*>(xb)[t] = o;
}

// transpose+cast weights: Wt[c][k] = (c<halfC ? Ws[k][c] : Wn[k][c-halfC]), row-major [2*halfC][K]
__global__ __launch_bounds__(256) void k_wt(const float* __restrict__ Ws, const float* __restrict__ Wn,
                                            int K, int logK, int halfC, unsigned short* __restrict__ Wt) {
    int t = blockIdx.x * blockDim.x + threadIdx.x;
    int total = 2 * halfC * K;
    if (t >= total) return;
    int c = t >> logK, k = t & (K - 1);
    float v = (c < halfC) ? Ws[(size_t)k * halfC + c] : Wn[(size_t)k * halfC + (c - halfC)];
    Wt[t] = f2bf(v);
}

// ---------------- bf16 MFMA GEMM ----------------
// C[Mpad x 2*halfC] = A[Mpad x K](bf16) @ Wt^T.  Wt is [2*halfC][K] row-major.
// cols < halfC -> Cself (f32), cols >= halfC -> Cneigh (bf16).
#define LDSK 40

__global__ __launch_bounds__(256) void gemm_mfma(const unsigned short* __restrict__ A, int K,
                                                 const unsigned short* __restrict__ Wt, int halfC,
                                                 float* __restrict__ Cself, unsigned short* __restrict__ Cneigh) {
    __shared__ unsigned short As[128 * LDSK];
    __shared__ unsigned short Bs[128 * LDSK];
    const int m0 = blockIdx.x * 128;
    const int n0 = blockIdx.y * 128;
    const int tid = threadIdx.x;
    const int wave = tid >> 6, lane = tid & 63;
    const int wm = wave >> 1, wn = wave & 1;
    const int l15 = lane & 15, l4 = lane >> 4;

    f32x4 acc[4][4] = {};

    for (int k0 = 0; k0 < K; k0 += 32) {
        #pragma unroll
        for (int t = 0; t < 2; ++t) {
            int task = tid + t * 256;
            int row = task >> 2, chunk = task & 3;
            const uint4 av = *reinterpret_cast<const uint4*>(&A[(size_t)(m0 + row) * K + k0 + chunk * 8]);
            *reinterpret_cast<uint4*>(&As[row * LDSK + chunk * 8]) = av;
            const uint4 bv = *reinterpret_cast<const uint4*>(&Wt[(size_t)(n0 + row) * K + k0 + chunk * 8]);
            *reinterpret_cast<uint4*>(&Bs[row * LDSK + chunk * 8]) = bv;
        }
        __syncthreads();
        short8 af[4], bfr[4];
        #pragma unroll
        for (int m = 0; m < 4; ++m)
            af[m] = *reinterpret_cast<const short8*>(&As[(wm * 64 + m * 16 + l15) * LDSK + l4 * 8]);
        #pragma unroll
        for (int n = 0; n < 4; ++n)
            bfr[n] = *reinterpret_cast<const short8*>(&Bs[(wn * 64 + n * 16 + l15) * LDSK + l4 * 8]);
        #pragma unroll
        for (int m = 0; m < 4; ++m)
            #pragma unroll
            for (int n = 0; n < 4; ++n)
                acc[m][n] = __builtin_amdgcn_mfma_f32_16x16x32_bf16(af[m], bfr[n], acc[m][n], 0, 0, 0);
        __syncthreads();
    }

    #pragma unroll
    for (int m = 0; m < 4; ++m) {
        #pragma unroll
        for (int n = 0; n < 4; ++n) {
            int cg = n0 + wn * 64 + n * 16 + l15;
            bool is_self = cg < halfC;
            #pragma unroll
            for (int r = 0; r < 4; ++r) {
                int rg = m0 + wm * 64 + m * 16 + l4 * 4 + r;
                float v = acc[m][n][r];
                if (is_self) Cself[(size_t)rg * halfC + cg] = v;
                else         Cneigh[(size_t)rg * halfC + (cg - halfC)] = f2bf(v);
            }
        }
    }
}

// ---------------- layer-1 aggregate + combine + relu -> h (bf16) ----------------
__global__ __launch_bounds__(256) void k_agg1(const uint32* __restrict__ t1n, const float* __restrict__ t1s,
                                              const int* __restrict__ rs, const int* __restrict__ ss,
                                              const float* __restrict__ dinv, const float* __restrict__ b1,
                                              uint32* __restrict__ h, int N) {
    int wid  = (blockIdx.x * blockDim.x + threadIdx.x) >> 6;
    int lane = threadIdx.x & 63;
    if (wid >= N) return;
    int e0 = rs[wid], e1 = rs[wid + 1];
    float ax = 0.f, ay = 0.f, bx = 0.f, by = 0.f;
    int e = e0;
    for (; e + 4 <= e1; e += 4) {
        int s0 = ss[e], s1 = ss[e + 1], s2 = ss[e + 2], s3 = ss[e + 3];
        uint32 v0 = t1n[(size_t)s0 * 64 + lane];
        uint32 v1 = t1n[(size_t)s1 * 64 + lane];
        uint32 v2 = t1n[(size_t)s2 * 64 + lane];
        uint32 v3 = t1n[(size_t)s3 * 64 + lane];
        ax += bf_lo(v0); ay += bf_hi(v0);
        bx += bf_lo(v1); by += bf_hi(v1);
        ax += bf_lo(v2); ay += bf_hi(v2);
        bx += bf_lo(v3); by += bf_hi(v3);
    }
    for (; e < e1; ++e) {
        uint32 v = t1n[(size_t)ss[e] * 64 + lane];
        ax += bf_lo(v); ay += bf_hi(v);
    }
    ax += bx; ay += by;
    float di = dinv[wid];
    float2 self = *reinterpret_cast<const float2*>(&t1s[(size_t)wid * 128 + lane * 2]);
    float2 bb   = *reinterpret_cast<const float2*>(&b1[lane * 2]);
    float hx = fmaxf(fmaf(ax, di, self.x) + bb.x, 0.f);
    float hy = fmaxf(fmaf(ay, di, self.y) + bb.y, 0.f);
    h[(size_t)wid * 64 + lane] = pack2bf(hx, hy);
}

// ---------------- layer-2 aggregate + combine -> out (f32) ----------------
__global__ __launch_bounds__(256) void k_agg2(const uint32* __restrict__ t2n, const float* __restrict__ t2s,
                                              const int* __restrict__ rs, const int* __restrict__ ss,
                                              const float* __restrict__ dinv, const float* __restrict__ b2,
                                              float* __restrict__ out, int N) {
    int node = (blockIdx.x * blockDim.x + threadIdx.x) >> 5;
    int lane = threadIdx.x & 31;
    if (node >= N) return;
    int e0 = rs[node], e1 = rs[node + 1];
    float ax = 0.f, ay = 0.f, bx = 0.f, by = 0.f;
    int e = e0;
    for (; e + 4 <= e1; e += 4) {
        int s0 = ss[e], s1 = ss[e + 1], s2 = ss[e + 2], s3 = ss[e + 3];
        uint32 v0 = t2n[(size_t)s0 * 32 + lane];
        uint32 v1 = t2n[(size_t)s1 * 32 + lane];
        uint32 v2 = t2n[(size_t)s2 * 32 + lane];
        uint32 v3 = t2n[(size_t)s3 * 32 + lane];
        ax += bf_lo(v0); ay += bf_hi(v0);
        bx += bf_lo(v1); by += bf_hi(v1);
        ax += bf_lo(v2); ay += bf_hi(v2);
        bx += bf_lo(v3); by += bf_hi(v3);
    }
    for (; e < e1; ++e) {
        uint32 v = t2n[(size_t)ss[e] * 32 + lane];
        ax += bf_lo(v); ay += bf_hi(v);
    }
    ax += bx; ay += by;
    float di = dinv[node];
    float2 self = *reinterpret_cast<const float2*>(&t2s[(size_t)node * 64 + lane * 2]);
    float2 bb   = *reinterpret_cast<const float2*>(&b2[lane * 2]);
    float2 o;
    o.x = fmaf(ax, di, self.x) + bb.x;
    o.y = fmaf(ay, di, self.y) + bb.y;
    *reinterpret_cast<float2*>(&out[(size_t)node * 64 + lane * 2]) = o;
}

extern "C" void kernel_launch(void* const* d_in, const int* in_sizes, int n_in,
                              void* d_out, int out_size, void* d_ws, size_t ws_size,
                              hipStream_t stream) {
    const float* x   = (const float*)d_in[0];
    const int*   src = (const int*)d_in[1];
    const int*   dst = (const int*)d_in[2];
    const float* W1s = (const float*)d_in[3];
    const float* W1n = (const float*)d_in[4];
    const float* b1  = (const float*)d_in[5];
    const float* W2s = (const float*)d_in[6];
    const float* W2n = (const float*)d_in[7];
    const float* b2  = (const float*)d_in[8];
    float* out = (float*)d_out;

    const int IN = 256, H = 128, OUT = 64;
    const int N  = in_sizes[0] / IN;
    const int E  = in_sizes[1];
    const int Mpad = (N + 127) & ~127;
    const int NB = (N + 127) >> 7;

    char* ws = (char*)d_ws;
    size_t off = 0;
    auto alloc = [&](size_t bytes) -> char* {
        char* p = ws + off;
        off = (off + bytes + 255) & ~(size_t)255;
        return p;
    };
    int*   row_start  = (int*)  alloc((size_t)(N + 1) * 4);
    float* deg_inv    = (float*)alloc((size_t)N * 4);
    int*   bcnt       = (int*)  alloc((size_t)NBMAX * 4);
    int*   boffs      = (int*)  alloc((size_t)(NBMAX + 1) * 4);
    int*   gfill      = (int*)  alloc((size_t)NBMAX * 4);
    int*   src_sorted = (int*)  alloc((size_t)E * 4);
    unsigned short* xb  = (unsigned short*)alloc((size_t)Mpad * IN * 2);     // bf16 x
    unsigned short* Wt1 = (unsigned short*)alloc((size_t)(2 * H) * IN * 2);
    unsigned short* Wt2 = (unsigned short*)alloc((size_t)(2 * OUT) * H * 2);
    float*          t1s = (float*)         alloc((size_t)Mpad * H * 4);      // reused as t2s
    unsigned short* t1n = (unsigned short*)alloc((size_t)Mpad * H * 2);      // reused as t2n
    unsigned short* hbf = (unsigned short*)alloc((size_t)Mpad * H * 2);

    // pairs buffer aliases xb: consumed by k_bucket_sort BEFORE k_cast_x writes xb (stream-ordered)
    uint32* pairs = (uint32*)xb;

    // 1. CSR build via two-level bucket sort
    hipMemsetAsync(bcnt, 0, (size_t)NBMAX * 4, stream);
    int nblk = (E + EPB - 1) / EPB;
    k_bucket_count  <<<nblk, 256, 0, stream>>>(dst, E, bcnt);
    k_bucket_scan   <<<1, 1024, 0, stream>>>(bcnt, NB, boffs, gfill, E);
    k_bucket_scatter<<<nblk, 256, 0, stream>>>(src, dst, E, gfill, pairs);
    k_bucket_sort   <<<NB, 256, 0, stream>>>(pairs, boffs, N, E, row_start, deg_inv, src_sorted);

    // 2. casts (k_cast_x overwrites the pairs region -- safe, pairs already consumed)
    long total8 = (long)N * IN / 8;
    k_cast_x<<<(int)((total8 + 255) / 256), 256, 0, stream>>>(x, (uint32*)xb, total8);
    k_wt<<<(2 * H * IN + 255) / 256, 256, 0, stream>>>(W1s, W1n, IN, 8, H, Wt1);
    k_wt<<<(2 * OUT * H + 255) / 256, 256, 0, stream>>>(W2s, W2n, H, 7, OUT, Wt2);

    // 3. layer 1 GEMM -> self f32 [Mpad x 128] + neigh bf16 [Mpad x 128]
    gemm_mfma<<<dim3(Mpad / 128, 2), 256, 0, stream>>>(xb, IN, Wt1, H, t1s, t1n);
    // 4. aggregate + relu -> h bf16
    k_agg1<<<(N + 3) / 4, 256, 0, stream>>>((const uint32*)t1n, t1s, row_start, src_sorted, deg_inv, b1,
                                            (uint32*)hbf, N);
    // 5. layer 2 GEMM -> self f32 [Mpad x 64] + neigh bf16 [Mpad x 64]
    gemm_mfma<<<dim3(Mpad / 128, 1), 256, 0, stream>>>(hbf, H, Wt2, OUT, t1s, t1n);
    // 6. aggregate -> out f32
    k_agg2<<<(N + 7) / 8, 256, 0, stream>>>((const uint32*)t1n, t1s, row_start, src_sorted, deg_inv, b2,
                                            out, N);
}

// Round 4
// 405.445 us; speedup vs baseline: 3.0165x; 1.0478x over previous
//
#include <hip/hip_runtime.h>
#include <hip/hip_bf16.h>

// GraphSAGE 2-layer: bucket-sort CSR build + bf16 MFMA transform-then-aggregate.
// N=100000, E=3.2M, IN=256, H=128, OUT=64.
// agg kernels: 16B/lane row gathers, 8 edges in flight, shfl_xor combine.

typedef unsigned int uint32;
typedef __attribute__((ext_vector_type(8))) short short8;
typedef __attribute__((ext_vector_type(4))) float f32x4;

#define NBMAX 1024     // max buckets (N <= 131072 at 128 nodes/bucket)
#define EPB   16384    // edges per block in bucket count/scatter

__device__ __forceinline__ unsigned short f2bf(float f) {
    unsigned u = __float_as_uint(f);
    u += 0x7fffu + ((u >> 16) & 1u);      // RNE
    return (unsigned short)(u >> 16);
}
__device__ __forceinline__ uint32 pack2bf(float lo, float hi) {
    return (uint32)f2bf(lo) | ((uint32)f2bf(hi) << 16);
}
__device__ __forceinline__ float bf_lo(uint32 v) { return __uint_as_float(v << 16); }
__device__ __forceinline__ float bf_hi(uint32 v) { return __uint_as_float(v & 0xFFFF0000u); }

// ---------------- bucket-sort CSR build (bucket = dst >> 7) ----------------
__global__ __launch_bounds__(256) void k_bucket_count(const int* __restrict__ dst, int E,
                                                      int* __restrict__ bcnt) {
    __shared__ int hist[NBMAX];
    for (int i = threadIdx.x; i < NBMAX; i += 256) hist[i] = 0;
    __syncthreads();
    int base = blockIdx.x * EPB;
    #pragma unroll 4
    for (int i = 0; i < 64; ++i) {
        int e = base + i * 256 + threadIdx.x;
        if (e < E) atomicAdd(&hist[dst[e] >> 7], 1);
    }
    __syncthreads();
    for (int i = threadIdx.x; i < NBMAX; i += 256) {
        int h = hist[i];
        if (h) atomicAdd(&bcnt[i], h);
    }
}

__global__ __launch_bounds__(1024) void k_bucket_scan(const int* __restrict__ bcnt, int NB,
                                                      int* __restrict__ boffs, int* __restrict__ gfill,
                                                      int E) {
    __shared__ int sd[1024];
    int tid = threadIdx.x;
    int v = (tid < NB) ? bcnt[tid] : 0;
    sd[tid] = v;
    __syncthreads();
    for (int off = 1; off < 1024; off <<= 1) {
        int t = (tid >= off) ? sd[tid - off] : 0;
        __syncthreads();
        sd[tid] += t;
        __syncthreads();
    }
    int excl = sd[tid] - v;
    if (tid < NB) { boffs[tid] = excl; gfill[tid] = excl; }
    if (tid == 0) boffs[NB] = E;
}

__global__ __launch_bounds__(256) void k_bucket_scatter(const int* __restrict__ src,
                                                        const int* __restrict__ dst, int E,
                                                        int* __restrict__ gfill,
                                                        uint32* __restrict__ pairs) {
    __shared__ int hist[NBMAX];
    __shared__ int basea[NBMAX];
    for (int i = threadIdx.x; i < NBMAX; i += 256) hist[i] = 0;
    __syncthreads();
    int base = blockIdx.x * EPB;
    #pragma unroll 4
    for (int i = 0; i < 64; ++i) {
        int e = base + i * 256 + threadIdx.x;
        if (e < E) atomicAdd(&hist[dst[e] >> 7], 1);
    }
    __syncthreads();
    for (int i = threadIdx.x; i < NBMAX; i += 256) {
        int h = hist[i];
        basea[i] = h ? atomicAdd(&gfill[i], h) : 0;
        hist[i] = 0;   // reuse as per-bucket fill
    }
    __syncthreads();
    #pragma unroll 4
    for (int i = 0; i < 64; ++i) {
        int e = base + i * 256 + threadIdx.x;
        if (e < E) {
            int d = dst[e];
            int b = d >> 7;
            int pos = basea[b] + atomicAdd(&hist[b], 1);
            pairs[pos] = ((uint32)src[e] << 7) | (uint32)(d & 127);
        }
    }
}

__global__ __launch_bounds__(256) void k_bucket_sort(const uint32* __restrict__ pairs,
                                                     const int* __restrict__ boffs,
                                                     int N, int E,
                                                     int* __restrict__ row_start,
                                                     float* __restrict__ deg_inv,
                                                     int* __restrict__ src_sorted) {
    __shared__ int cnt[128];
    __shared__ int sc[128];
    __shared__ int fill[128];
    int b = blockIdx.x, tid = threadIdx.x;
    int s0 = boffs[b], s1 = boffs[b + 1];
    if (tid < 128) cnt[tid] = 0;
    __syncthreads();
    for (int e = s0 + tid; e < s1; e += 256)
        atomicAdd(&cnt[pairs[e] & 127], 1);
    __syncthreads();
    if (tid < 128) sc[tid] = cnt[tid];
    __syncthreads();
    for (int off = 1; off < 128; off <<= 1) {
        int v = 0;
        if (tid < 128 && tid >= off) v = sc[tid - off];
        __syncthreads();
        if (tid < 128) sc[tid] += v;
        __syncthreads();
    }
    if (tid < 128) {
        int excl = sc[tid] - cnt[tid];
        int node = b * 128 + tid;
        if (node < N) {
            row_start[node] = s0 + excl;
            int d = cnt[tid];
            deg_inv[node] = 1.0f / (float)(d > 1 ? d : 1);
        }
        fill[tid] = s0 + excl;
    }
    if (b == 0 && tid == 0) row_start[N] = E;
    __syncthreads();
    for (int e = s0 + tid; e < s1; e += 256) {
        uint32 p = pairs[e];
        int pos = atomicAdd(&fill[p & 127], 1);
        src_sorted[pos] = (int)(p >> 7);
    }
}

// transpose+cast weights: Wt[c][k] = (c<halfC ? Ws[k][c] : Wn[k][c-halfC]), row-major [2*halfC][K]
__global__ __launch_bounds__(256) void k_wt(const float* __restrict__ Ws, const float* __restrict__ Wn,
                                            int K, int logK, int halfC, unsigned short* __restrict__ Wt) {
    int t = blockIdx.x * blockDim.x + threadIdx.x;
    int total = 2 * halfC * K;
    if (t >= total) return;
    int c = t >> logK, k = t & (K - 1);
    float v = (c < halfC) ? Ws[(size_t)k * halfC + c] : Wn[(size_t)k * halfC + (c - halfC)];
    Wt[t] = f2bf(v);
}

// ---------------- bf16 MFMA GEMM, full-width BN, bf16 outputs ----------------
// C[M x 2*halfC] = A[M x K] @ Wt^T.  Wt row-major [2*halfC][K], 2*halfC == BN == NREP*32.
// AF32: A is f32, converted to bf16 during LDS staging (fused cast).
// cols < halfC -> Cs (bf16), cols >= halfC -> Cn (bf16). 256 thr = 4 waves (2x2), wave tile 64 x BN/2.
#define LDSK 40

template<int NREP, bool AF32>
__global__ __launch_bounds__(256) void gemm_mfma(const void* __restrict__ Aptr, int Mrows, int K,
                                                 const unsigned short* __restrict__ Wt, int halfC,
                                                 unsigned short* __restrict__ Cs,
                                                 unsigned short* __restrict__ Cn) {
    constexpr int BN = NREP * 32;
    __shared__ unsigned short As[128 * LDSK];
    __shared__ unsigned short Bs[BN * LDSK];
    const int m0 = blockIdx.x * 128;
    const int tid = threadIdx.x;
    const int wave = tid >> 6, lane = tid & 63;
    const int wm = wave >> 1, wn = wave & 1;
    const int l15 = lane & 15, l4 = lane >> 4;

    f32x4 acc[4][NREP] = {};

    for (int k0 = 0; k0 < K; k0 += 32) {
        if constexpr (AF32) {
            const float* A = (const float*)Aptr;
            #pragma unroll
            for (int t = 0; t < 4; ++t) {          // 1024 tasks: row=task>>3, quad=task&7
                int task = tid + t * 256;
                int row = task >> 3, q = task & 7;
                int grow = m0 + row;
                float4 v = make_float4(0.f, 0.f, 0.f, 0.f);
                if (grow < Mrows) v = *reinterpret_cast<const float4*>(&A[(size_t)grow * K + k0 + q * 4]);
                uint2 o;
                o.x = pack2bf(v.x, v.y); o.y = pack2bf(v.z, v.w);
                *reinterpret_cast<uint2*>(&As[row * LDSK + q * 4]) = o;
            }
        } else {
            const unsigned short* A = (const unsigned short*)Aptr;
            #pragma unroll
            for (int t = 0; t < 2; ++t) {          // 512 tasks: row=task>>2, chunk=task&3
                int task = tid + t * 256;
                int row = task >> 2, chunk = task & 3;
                int grow = m0 + row;
                uint4 v = make_uint4(0u, 0u, 0u, 0u);
                if (grow < Mrows) v = *reinterpret_cast<const uint4*>(&A[(size_t)grow * K + k0 + chunk * 8]);
                *reinterpret_cast<uint4*>(&As[row * LDSK + chunk * 8]) = v;
            }
        }
        #pragma unroll
        for (int t = 0; t < BN / 64; ++t) {        // BN*4 tasks
            int task = tid + t * 256;
            int row = task >> 2, chunk = task & 3;
            uint4 v = *reinterpret_cast<const uint4*>(&Wt[(size_t)row * K + k0 + chunk * 8]);
            *reinterpret_cast<uint4*>(&Bs[row * LDSK + chunk * 8]) = v;
        }
        __syncthreads();
        short8 af[4];
        #pragma unroll
        for (int m = 0; m < 4; ++m)
            af[m] = *reinterpret_cast<const short8*>(&As[(wm * 64 + m * 16 + l15) * LDSK + l4 * 8]);
        #pragma unroll
        for (int n = 0; n < NREP; ++n) {
            short8 bfr = *reinterpret_cast<const short8*>(&Bs[(wn * (BN / 2) + n * 16 + l15) * LDSK + l4 * 8]);
            #pragma unroll
            for (int m = 0; m < 4; ++m)
                acc[m][n] = __builtin_amdgcn_mfma_f32_16x16x32_bf16(af[m], bfr, acc[m][n], 0, 0, 0);
        }
        __syncthreads();
    }

    #pragma unroll
    for (int m = 0; m < 4; ++m) {
        #pragma unroll
        for (int n = 0; n < NREP; ++n) {
            int cg = wn * (BN / 2) + n * 16 + l15;
            bool is_self = cg < halfC;
            unsigned short* dp = is_self ? Cs : Cn;
            int cl = is_self ? cg : cg - halfC;
            #pragma unroll
            for (int r = 0; r < 4; ++r) {
                int rg = m0 + wm * 64 + m * 16 + l4 * 4 + r;
                dp[(size_t)rg * halfC + cl] = f2bf(acc[m][n][r]);
            }
        }
    }
}

// ---------------- layer-1 aggregate + combine + relu -> h (bf16) ----------------
// one wave/node; 16 lanes per row (uint4 = 8 bf16 cols), 4 edges/iter, unroll 2 -> 8 in flight.
__global__ __launch_bounds__(256) void k_agg1(const uint4* __restrict__ t1n, const uint4* __restrict__ t1s,
                                              const int* __restrict__ rs, const int* __restrict__ ss,
                                              const float* __restrict__ dinv, const float* __restrict__ b1,
                                              uint4* __restrict__ h, int N) {
    int wid  = (blockIdx.x * blockDim.x + threadIdx.x) >> 6;
    int lane = threadIdx.x & 63;
    if (wid >= N) return;
    int e0 = rs[wid], e1 = rs[wid + 1];
    const int q = lane >> 4, c = lane & 15;
    float a0 = 0, a1 = 0, a2 = 0, a3 = 0, a4 = 0, a5 = 0, a6 = 0, a7 = 0;
    int e = e0;
    for (; e + 8 <= e1; e += 8) {
        int sA = ss[e + q];
        int sB = ss[e + 4 + q];
        uint4 vA = t1n[(size_t)sA * 16 + c];
        uint4 vB = t1n[(size_t)sB * 16 + c];
        a0 += bf_lo(vA.x); a1 += bf_hi(vA.x); a2 += bf_lo(vA.y); a3 += bf_hi(vA.y);
        a4 += bf_lo(vA.z); a5 += bf_hi(vA.z); a6 += bf_lo(vA.w); a7 += bf_hi(vA.w);
        a0 += bf_lo(vB.x); a1 += bf_hi(vB.x); a2 += bf_lo(vB.y); a3 += bf_hi(vB.y);
        a4 += bf_lo(vB.z); a5 += bf_hi(vB.z); a6 += bf_lo(vB.w); a7 += bf_hi(vB.w);
    }
    for (; e < e1; e += 4) {
        if (e + q < e1) {
            int s = ss[e + q];
            uint4 v = t1n[(size_t)s * 16 + c];
            a0 += bf_lo(v.x); a1 += bf_hi(v.x); a2 += bf_lo(v.y); a3 += bf_hi(v.y);
            a4 += bf_lo(v.z); a5 += bf_hi(v.z); a6 += bf_lo(v.w); a7 += bf_hi(v.w);
        }
    }
    a0 += __shfl_xor(a0, 16); a1 += __shfl_xor(a1, 16); a2 += __shfl_xor(a2, 16); a3 += __shfl_xor(a3, 16);
    a4 += __shfl_xor(a4, 16); a5 += __shfl_xor(a5, 16); a6 += __shfl_xor(a6, 16); a7 += __shfl_xor(a7, 16);
    a0 += __shfl_xor(a0, 32); a1 += __shfl_xor(a1, 32); a2 += __shfl_xor(a2, 32); a3 += __shfl_xor(a3, 32);
    a4 += __shfl_xor(a4, 32); a5 += __shfl_xor(a5, 32); a6 += __shfl_xor(a6, 32); a7 += __shfl_xor(a7, 32);
    if (lane < 16) {
        float di = dinv[wid];
        uint4 sv = t1s[(size_t)wid * 16 + c];
        float4 bA = *reinterpret_cast<const float4*>(&b1[c * 8]);
        float4 bB = *reinterpret_cast<const float4*>(&b1[c * 8 + 4]);
        float h0 = fmaxf(fmaf(a0, di, bf_lo(sv.x)) + bA.x, 0.f);
        float h1 = fmaxf(fmaf(a1, di, bf_hi(sv.x)) + bA.y, 0.f);
        float h2 = fmaxf(fmaf(a2, di, bf_lo(sv.y)) + bA.z, 0.f);
        float h3 = fmaxf(fmaf(a3, di, bf_hi(sv.y)) + bA.w, 0.f);
        float h4 = fmaxf(fmaf(a4, di, bf_lo(sv.z)) + bB.x, 0.f);
        float h5 = fmaxf(fmaf(a5, di, bf_hi(sv.z)) + bB.y, 0.f);
        float h6 = fmaxf(fmaf(a6, di, bf_lo(sv.w)) + bB.z, 0.f);
        float h7 = fmaxf(fmaf(a7, di, bf_hi(sv.w)) + bB.w, 0.f);
        uint4 o;
        o.x = pack2bf(h0, h1); o.y = pack2bf(h2, h3);
        o.z = pack2bf(h4, h5); o.w = pack2bf(h6, h7);
        h[(size_t)wid * 16 + c] = o;
    }
}

// ---------------- layer-2 aggregate + combine -> out (f32) ----------------
// one wave/node; 8 lanes per row (uint4), 8 edges/iter, unroll 2 -> 16 in flight.
__global__ __launch_bounds__(256) void k_agg2(const uint4* __restrict__ t2n, const uint4* __restrict__ t2s,
                                              const int* __restrict__ rs, const int* __restrict__ ss,
                                              const float* __restrict__ dinv, const float* __restrict__ b2,
                                              float* __restrict__ out, int N) {
    int wid  = (blockIdx.x * blockDim.x + threadIdx.x) >> 6;
    int lane = threadIdx.x & 63;
    if (wid >= N) return;
    int e0 = rs[wid], e1 = rs[wid + 1];
    const int o8 = lane >> 3, c = lane & 7;
    float a0 = 0, a1 = 0, a2 = 0, a3 = 0, a4 = 0, a5 = 0, a6 = 0, a7 = 0;
    int e = e0;
    for (; e + 16 <= e1; e += 16) {
        int sA = ss[e + o8];
        int sB = ss[e + 8 + o8];
        uint4 vA = t2n[(size_t)sA * 8 + c];
        uint4 vB = t2n[(size_t)sB * 8 + c];
        a0 += bf_lo(vA.x); a1 += bf_hi(vA.x); a2 += bf_lo(vA.y); a3 += bf_hi(vA.y);
        a4 += bf_lo(vA.z); a5 += bf_hi(vA.z); a6 += bf_lo(vA.w); a7 += bf_hi(vA.w);
        a0 += bf_lo(vB.x); a1 += bf_hi(vB.x); a2 += bf_lo(vB.y); a3 += bf_hi(vB.y);
        a4 += bf_lo(vB.z); a5 += bf_hi(vB.z); a6 += bf_lo(vB.w); a7 += bf_hi(vB.w);
    }
    for (; e < e1; e += 8) {
        if (e + o8 < e1) {
            int s = ss[e + o8];
            uint4 v = t2n[(size_t)s * 8 + c];
            a0 += bf_lo(v.x); a1 += bf_hi(v.x); a2 += bf_lo(v.y); a3 += bf_hi(v.y);
            a4 += bf_lo(v.z); a5 += bf_hi(v.z); a6 += bf_lo(v.w); a7 += bf_hi(v.w);
        }
    }
    a0 += __shfl_xor(a0, 8);  a1 += __shfl_xor(a1, 8);  a2 += __shfl_xor(a2, 8);  a3 += __shfl_xor(a3, 8);
    a4 += __shfl_xor(a4, 8);  a5 += __shfl_xor(a5, 8);  a6 += __shfl_xor(a6, 8);  a7 += __shfl_xor(a7, 8);
    a0 += __shfl_xor(a0, 16); a1 += __shfl_xor(a1, 16); a2 += __shfl_xor(a2, 16); a3 += __shfl_xor(a3, 16);
    a4 += __shfl_xor(a4, 16); a5 += __shfl_xor(a5, 16); a6 += __shfl_xor(a6, 16); a7 += __shfl_xor(a7, 16);
    a0 += __shfl_xor(a0, 32); a1 += __shfl_xor(a1, 32); a2 += __shfl_xor(a2, 32); a3 += __shfl_xor(a3, 32);
    a4 += __shfl_xor(a4, 32); a5 += __shfl_xor(a5, 32); a6 += __shfl_xor(a6, 32); a7 += __shfl_xor(a7, 32);
    if (lane < 8) {
        float di = dinv[wid];
        uint4 sv = t2s[(size_t)wid * 8 + c];
        float4 bA = *reinterpret_cast<const float4*>(&b2[c * 8]);
        float4 bB = *reinterpret_cast<const float4*>(&b2[c * 8 + 4]);
        float4 oA, oB;
        oA.x = fmaf(a0, di, bf_lo(sv.x)) + bA.x;
        oA.y = fmaf(a1, di, bf_hi(sv.x)) + bA.y;
        oA.z = fmaf(a2, di, bf_lo(sv.y)) + bA.z;
        oA.w = fmaf(a3, di, bf_hi(sv.y)) + bA.w;
        oB.x = fmaf(a4, di, bf_lo(sv.z)) + bB.x;
        oB.y = fmaf(a5, di, bf_hi(sv.z)) + bB.y;
        oB.z = fmaf(a6, di, bf_lo(sv.w)) + bB.z;
        oB.w = fmaf(a7, di, bf_hi(sv.w)) + bB.w;
        *reinterpret_cast<float4*>(&out[(size_t)wid * 64 + c * 8]) = oA;
        *reinterpret_cast<float4*>(&out[(size_t)wid * 64 + c * 8 + 4]) = oB;
    }
}

extern "C" void kernel_launch(void* const* d_in, const int* in_sizes, int n_in,
                              void* d_out, int out_size, void* d_ws, size_t ws_size,
                              hipStream_t stream) {
    const float* x   = (const float*)d_in[0];
    const int*   src = (const int*)d_in[1];
    const int*   dst = (const int*)d_in[2];
    const float* W1s = (const float*)d_in[3];
    const float* W1n = (const float*)d_in[4];
    const float* b1  = (const float*)d_in[5];
    const float* W2s = (const float*)d_in[6];
    const float* W2n = (const float*)d_in[7];
    const float* b2  = (const float*)d_in[8];
    float* out = (float*)d_out;

    const int IN = 256, H = 128, OUT = 64;
    const int N  = in_sizes[0] / IN;
    const int E  = in_sizes[1];
    const int Mpad = (N + 127) & ~127;
    const int NB = (N + 127) >> 7;

    char* ws = (char*)d_ws;
    size_t off = 0;
    auto alloc = [&](size_t bytes) -> char* {
        char* p = ws + off;
        off = (off + bytes + 255) & ~(size_t)255;
        return p;
    };
    int*   row_start  = (int*)  alloc((size_t)(N + 1) * 4);
    float* deg_inv    = (float*)alloc((size_t)N * 4);
    int*   bcnt       = (int*)  alloc((size_t)NBMAX * 4);
    int*   boffs      = (int*)  alloc((size_t)(NBMAX + 1) * 4);
    int*   gfill      = (int*)  alloc((size_t)NBMAX * 4);
    int*   src_sorted = (int*)  alloc((size_t)E * 4);
    uint32* pairs     = (uint32*)alloc((size_t)E * 4);
    unsigned short* Wt1 = (unsigned short*)alloc((size_t)(2 * H) * IN * 2);
    unsigned short* Wt2 = (unsigned short*)alloc((size_t)(2 * OUT) * H * 2);
    unsigned short* t1s = (unsigned short*)alloc((size_t)Mpad * H * 2);   // bf16 self; reused layer2
    unsigned short* t1n = (unsigned short*)alloc((size_t)Mpad * H * 2);   // bf16 neigh; reused layer2
    unsigned short* hbf = (unsigned short*)alloc((size_t)Mpad * H * 2);   // layer-1 output

    // 1. CSR build via two-level bucket sort
    hipMemsetAsync(bcnt, 0, (size_t)NBMAX * 4, stream);
    int nblk = (E + EPB - 1) / EPB;
    k_bucket_count  <<<nblk, 256, 0, stream>>>(dst, E, bcnt);
    k_bucket_scan   <<<1, 1024, 0, stream>>>(bcnt, NB, boffs, gfill, E);
    k_bucket_scatter<<<nblk, 256, 0, stream>>>(src, dst, E, gfill, pairs);
    k_bucket_sort   <<<NB, 256, 0, stream>>>(pairs, boffs, N, E, row_start, deg_inv, src_sorted);

    // 2. weight transpose+cast
    k_wt<<<(2 * H * IN + 255) / 256, 256, 0, stream>>>(W1s, W1n, IN, 8, H, Wt1);
    k_wt<<<(2 * OUT * H + 255) / 256, 256, 0, stream>>>(W2s, W2n, H, 7, OUT, Wt2);

    // 3. layer 1 GEMM (fused f32->bf16 cast): x[N x 256] -> t1s/t1n bf16 [Mpad x 128] each
    gemm_mfma<8, true><<<Mpad / 128, 256, 0, stream>>>(x, N, IN, Wt1, H, t1s, t1n);
    // 4. aggregate + relu -> h bf16
    k_agg1<<<(N + 3) / 4, 256, 0, stream>>>((const uint4*)t1n, (const uint4*)t1s,
                                            row_start, src_sorted, deg_inv, b1, (uint4*)hbf, N);
    // 5. layer 2 GEMM: hbf[Mpad x 128] -> t2s/t2n bf16 [Mpad x 64] each (reuse t1s/t1n)
    gemm_mfma<4, false><<<Mpad / 128, 256, 0, stream>>>(hbf, Mpad, H, Wt2, OUT, t1s, t1n);
    // 6. aggregate -> out f32
    k_agg2<<<(N + 3) / 4, 256, 0, stream>>>((const uint4*)t1n, (const uint4*)t1s,
                                            row_start, src_sorted, deg_inv, b2, out, N);
}